// Round 5
// baseline (407.509 us; speedup 1.0000x reference)
//
#include <hip/hip_runtime.h>
#include <stdint.h>

// DreamGraphReasoner on MI355X (gfx950)
// Residual stream kept bf16-only (xb). Exact f32 mean maintained separately:
// mean(x3) = mean(x0) + sum_h mean(t_h), with partial sums fused into
// nodes_kernel (x0) and attn_mix (t_h, LDS-accumulated per block).
// Sparse attention: node n=(g,l) attends to {(g',l): g'!=g} U {(g,l+1) if l<63}
// Fusion: attended@Whop = attn@(V@Whop)  =>  QKV GEMM emits Q|K|VW_h directly.

typedef __bf16 bf16;
typedef __bf16 bf16x8 __attribute__((ext_vector_type(8)));
typedef __bf16 bf16x4 __attribute__((ext_vector_type(4)));
typedef float  f32x4  __attribute__((ext_vector_type(4)));

__device__ __forceinline__ void gload_lds16(const void* g, void* l) {
  __builtin_amdgcn_global_load_lds(
      (__attribute__((address_space(1))) void*)(size_t)(g),
      (__attribute__((address_space(3))) void*)(l), 16, 0, 0);
}

// ---------------- weight prep (coalesced reads; scattered writes L2-combine) --
__global__ void prep_weights(const float* __restrict__ Wq, const float* __restrict__ Wk,
                             const float* __restrict__ bq, const float* __restrict__ bk,
                             const float* __restrict__ Wv, const float* __restrict__ Whop,
                             const float* __restrict__ W1, const float* __restrict__ W2,
                             bf16* __restrict__ WtQK, float* __restrict__ bcat,
                             bf16* __restrict__ WhopTb, bf16* __restrict__ Wvb,
                             float* __restrict__ W1t, float* __restrict__ W2t) {
  int t = blockIdx.x * 256 + threadIdx.x;
  if (t < 524288) {                        // WtQK[sel*512+c][k] = W[k][c]
    int sel = t >> 18, k = (t >> 9) & 511, c = t & 511;
    const float* W = sel ? Wk : Wq;
    WtQK[(size_t)(sel * 512 + c) * 512 + k] = (bf16)W[k * 512 + c];
  } else if (t < 1048576) {                // W1t[o][d] = W1[d][o]
    int u = t - 524288;
    int d = u >> 10, o = u & 1023;
    W1t[(size_t)o * 512 + d] = W1[d * 1024 + o];
  } else if (t < 1572864) {                // W2t[o][d] = W2[d][o]
    int u = t - 1048576;
    int d = u >> 9, o = u & 511;
    W2t[(size_t)o * 1024 + d] = W2[d * 512 + o];
  } else if (t < 1573888) {
    int u = t - 1572864;
    bcat[u] = (u < 512) ? bq[u] : bk[u - 512];
  } else if (t < 2360320) {                // WhopTb[h*512+c][d] = Whop[h][d][c]
    int u = t - 1573888;
    int h = u >> 18, rem = u & 262143;
    int d = rem >> 9, c = rem & 511;
    WhopTb[(size_t)h * 262144 + (size_t)c * 512 + d] = (bf16)Whop[h * 262144 + d * 512 + c];
  } else if (t < 2622464) {                // Wvb = bf16(Wv)
    int u = t - 2360320;
    Wvb[u] = (bf16)Wv[u];
  }
}

// ---------------- bvw[h][c] = sum_d bv[d] * Whop[h][d][c]  (wave per output) --
__global__ __launch_bounds__(256)
void bvw_kernel(const float* __restrict__ bv, const float* __restrict__ Whop,
                float* __restrict__ bvw) {
  int w = blockIdx.x * 4 + (threadIdx.x >> 6);  // 0..1535
  int lane = threadIdx.x & 63;
  int h = w >> 9, c = w & 511;
  int d0 = lane * 8;
  const float* wh = Whop + h * 262144 + c;
  float p = 0.f;
#pragma unroll
  for (int i = 0; i < 8; ++i) p += bv[d0 + i] * wh[(d0 + i) * 512];
#pragma unroll
  for (int off = 32; off; off >>= 1) p += __shfl_xor(p, off);
  if (lane == 0) bvw[w] = p;
}

// ---------------- node embeddings + fused x0 mean partials -------------------
// block (c, b): 8 nodes per chunk c, 128 threads (float4 over d)
__global__ __launch_bounds__(128)
void nodes_kernel(const float4* __restrict__ w, const float4* __restrict__ a,
                  const float4* __restrict__ r, bf16x4* __restrict__ xb,
                  float4* __restrict__ partial0) {
  const int c = blockIdx.x;   // 0..127
  const int b = blockIdx.y;   // 0..15
  const int dq = threadIdx.x; // 0..127 (d = dq*4)
  float4 s = (float4){0.f, 0.f, 0.f, 0.f};
#pragma unroll 2
  for (int n = c * 8; n < c * 8 + 8; ++n) {
    size_t idx = ((size_t)(n * 16 + b)) * 128 + dq;   // float4 index
    float4 vw = w[idx], va = a[idx], vr = r[idx];
    float4 v;
    v.x = (vw.x + va.x + vr.x) * (1.f / 3.f);
    v.y = (vw.y + va.y + vr.y) * (1.f / 3.f);
    v.z = (vw.z + va.z + vr.z) * (1.f / 3.f);
    v.w = (vw.w + va.w + vr.w) * (1.f / 3.f);
    bf16x4 bv4;
    bv4[0] = (bf16)v.x; bv4[1] = (bf16)v.y; bv4[2] = (bf16)v.z; bv4[3] = (bf16)v.w;
    xb[idx] = bv4;
    s.x += v.x; s.y += v.y; s.z += v.z; s.w += v.w;
  }
  partial0[((size_t)c * 16 + b) * 128 + dq] = s;
}

// ---------------- plain bf16 MFMA GEMM: out(1536x512) = A @ Bt^T -------------
__global__ __launch_bounds__(256)
void gemm_plain(const bf16* __restrict__ A, const bf16* __restrict__ Bt,
                bf16* __restrict__ out) {
  constexpr int BK = 32;
  __shared__ __align__(16) bf16 As[128 * BK];
  __shared__ __align__(16) bf16 Bs[128 * BK];
  const int tid = threadIdx.x;
  const int wave = tid >> 6, lane = tid & 63;
  const int wr = wave >> 1, wc = wave & 1;
  const int m0 = blockIdx.x * 128;
  const int n0 = blockIdx.y * 128;
  const int srow = lane >> 2;
  const int skg = ((lane & 3) ^ ((lane >> 3) & 3)) * 8;
  const int fr = lane & 15;
  const int kq = (((lane >> 4) ^ ((lane >> 1) & 3)) & 3) * 8;

  f32x4 acc[4][4];
#pragma unroll
  for (int i = 0; i < 4; ++i)
#pragma unroll
    for (int j = 0; j < 4; ++j) acc[i][j] = (f32x4){0.f, 0.f, 0.f, 0.f};

  for (int kt = 0; kt < 512; kt += BK) {
    __syncthreads();
#pragma unroll
    for (int i = 0; i < 2; ++i) {
      int ch = wave * 2 + i;
      int row = ch * 16 + srow;
      gload_lds16(A + (size_t)(m0 + row) * 512 + kt + skg, &As[ch * 16 * BK]);
      gload_lds16(Bt + (size_t)(n0 + row) * 512 + kt + skg, &Bs[ch * 16 * BK]);
    }
    __syncthreads();

    bf16x8 af[4], bg[4];
#pragma unroll
    for (int i = 0; i < 4; ++i)
      af[i] = *(const bf16x8*)&As[(wr * 64 + i * 16 + fr) * BK + kq];
#pragma unroll
    for (int j = 0; j < 4; ++j)
      bg[j] = *(const bf16x8*)&Bs[(wc * 64 + j * 16 + fr) * BK + kq];
#pragma unroll
    for (int i = 0; i < 4; ++i)
#pragma unroll
      for (int j = 0; j < 4; ++j)
        acc[i][j] = __builtin_amdgcn_mfma_f32_16x16x32_bf16(af[i], bg[j], acc[i][j], 0, 0, 0);
  }

#pragma unroll
  for (int i = 0; i < 4; ++i) {
    int grow0 = m0 + wr * 64 + i * 16 + (lane >> 4) * 4;
#pragma unroll
    for (int j = 0; j < 4; ++j) {
      int gcol = n0 + wc * 64 + j * 16 + fr;
#pragma unroll
      for (int q = 0; q < 4; ++q)
        out[(size_t)(grow0 + q) * 512 + gcol] = (bf16)acc[i][j][q];
    }
  }
}

// ---------------- bf16 MFMA GEMM: QKW = A(16384x512) @ [WqT|WkT|WvwT]^T + bias
__global__ __launch_bounds__(256)
void gemm_qkw(const bf16* __restrict__ A, const bf16* __restrict__ BtQK,
              const bf16* __restrict__ BtVW, const float* __restrict__ biasQK,
              const float* __restrict__ biasVW, bf16* __restrict__ out) {
  constexpr int BK = 32;
  __shared__ __align__(16) bf16 As[128 * BK];
  __shared__ __align__(16) bf16 Bs[128 * BK];
  const int tid = threadIdx.x;
  const int wave = tid >> 6, lane = tid & 63;
  const int wr = wave >> 1, wc = wave & 1;
  const int m0 = blockIdx.x * 128;
  const int n0 = blockIdx.y * 128;
  const bf16* Bt = (n0 < 1024) ? BtQK : (BtVW - (size_t)1024 * 512);
  const float* bias = (n0 < 1024) ? biasQK : (biasVW - 1024);

  const int srow = lane >> 2;
  const int skg = ((lane & 3) ^ ((lane >> 3) & 3)) * 8;
  const int fr = lane & 15;
  const int kq = (((lane >> 4) ^ ((lane >> 1) & 3)) & 3) * 8;

  f32x4 acc[4][4];
#pragma unroll
  for (int i = 0; i < 4; ++i)
#pragma unroll
    for (int j = 0; j < 4; ++j) acc[i][j] = (f32x4){0.f, 0.f, 0.f, 0.f};

  for (int kt = 0; kt < 512; kt += BK) {
    __syncthreads();
#pragma unroll
    for (int i = 0; i < 2; ++i) {
      int ch = wave * 2 + i;
      int row = ch * 16 + srow;
      gload_lds16(A + (size_t)(m0 + row) * 512 + kt + skg, &As[ch * 16 * BK]);
      gload_lds16(Bt + (size_t)(n0 + row) * 512 + kt + skg, &Bs[ch * 16 * BK]);
    }
    __syncthreads();

    bf16x8 af[4], bg[4];
#pragma unroll
    for (int i = 0; i < 4; ++i)
      af[i] = *(const bf16x8*)&As[(wr * 64 + i * 16 + fr) * BK + kq];
#pragma unroll
    for (int j = 0; j < 4; ++j)
      bg[j] = *(const bf16x8*)&Bs[(wc * 64 + j * 16 + fr) * BK + kq];
#pragma unroll
    for (int i = 0; i < 4; ++i)
#pragma unroll
      for (int j = 0; j < 4; ++j)
        acc[i][j] = __builtin_amdgcn_mfma_f32_16x16x32_bf16(af[i], bg[j], acc[i][j], 0, 0, 0);
  }

#pragma unroll
  for (int i = 0; i < 4; ++i) {
    int grow0 = m0 + wr * 64 + i * 16 + (lane >> 4) * 4;
#pragma unroll
    for (int j = 0; j < 4; ++j) {
      int gcol = n0 + wc * 64 + j * 16 + fr;
      float bvv = bias[gcol];
#pragma unroll
      for (int q = 0; q < 4; ++q)
        out[(size_t)(grow0 + q) * 1536 + gcol] = (bf16)(acc[i][j][q] + bvv);
    }
  }
}

// ---------------- sparse masked attention + hop epilogue + t-mean partials ---
// 512-thread blocks: 8 waves = 8 dreams per (l,b). XCD-chunked block swizzle.
// Epilogue: t = relu(mix + b_hop); xb += t (bf16 RMW); LDS-accumulate t-sum.
__global__ __launch_bounds__(512)
void attn_mix(const bf16* __restrict__ QKW, bf16* __restrict__ xb,
              const float* __restrict__ bhop, float* __restrict__ tpart,
              int first) {
  __shared__ float tsum[512];
  const int tid = threadIdx.x;
  tsum[tid] = 0.f;
  __syncthreads();

  const int bid = blockIdx.x;
  const int wid = ((bid & 7) << 8) | (bid >> 3);   // 2048/8 = 256 blocks per XCD
  const int lane = tid & 63;
  const int l = wid >> 5;
  const int b = (wid >> 1) & 15;
  const int g = ((wid & 1) << 3) | (tid >> 6);
  const int r = (((g << 6) | l) << 4) | b;

  bf16x8 qv = *(const bf16x8*)(QKW + (size_t)r * 1536 + lane * 8);
  float qf[8];
#pragma unroll
  for (int i = 0; i < 8; ++i) qf[i] = (float)qv[i];

  int rows[17];
#pragma unroll
  for (int j = 0; j < 16; ++j) rows[j] = (((j << 6) | l) << 4) | b;
  rows[16] = (l < 63) ? (r + 16) : r;

  float s[17];
#pragma unroll
  for (int j = 0; j < 17; ++j) {
    const bf16* Krow = QKW + (size_t)rows[j] * 1536 + 512;
    bf16x8 kv = *(const bf16x8*)(Krow + lane * 8);
    float p = 0.f;
#pragma unroll
    for (int i = 0; i < 8; ++i) p += qf[i] * (float)kv[i];
#pragma unroll
    for (int off = 32; off; off >>= 1) p += __shfl_xor(p, off);
    p *= 0.044194173824159216f;  // 1/sqrt(512)
    bool valid = (j < 16) ? (j != g) : (l < 63);
    s[j] = valid ? p : -1e30f;
  }

  float mx = -1e30f;
#pragma unroll
  for (int j = 0; j < 17; ++j) mx = fmaxf(mx, s[j]);
  float pr[17], sum = 0.f;
#pragma unroll
  for (int j = 0; j < 17; ++j) { pr[j] = __expf(s[j] - mx); sum += pr[j]; }
  float inv = 1.f / sum;

  float acc[8] = {0, 0, 0, 0, 0, 0, 0, 0};
#pragma unroll
  for (int j = 0; j < 17; ++j) {
    const bf16* Vrow = QKW + (size_t)rows[j] * 1536 + 1024;
    bf16x8 vv = *(const bf16x8*)(Vrow + lane * 8);
    float w = pr[j] * inv;
#pragma unroll
    for (int i = 0; i < 8; ++i) acc[i] += w * (float)vv[i];
  }

  // epilogue: t = relu(mix+bh); xb += t; accumulate t into block mean partial
  const int d0 = lane * 8;
  size_t idx = (size_t)r * 512 + d0;
  bf16x8 xo = *(const bf16x8*)(xb + idx);
  float4 bh0 = *(const float4*)(bhop + d0);
  float4 bh1 = *(const float4*)(bhop + d0 + 4);
  float bh[8] = {bh0.x, bh0.y, bh0.z, bh0.w, bh1.x, bh1.y, bh1.z, bh1.w};
  bf16x8 ov;
  float t[8];
#pragma unroll
  for (int i = 0; i < 8; ++i) {
    t[i] = fmaxf(acc[i] + bh[i], 0.f);
    ov[i] = (bf16)((float)xo[i] + t[i]);
  }
  *(bf16x8*)(xb + idx) = ov;
#pragma unroll
  for (int i = 0; i < 8; ++i) atomicAdd(&tsum[d0 + i], t[i]);
  __syncthreads();
  float* tp = tpart + (size_t)wid * 512 + tid;
  if (first) *tp = tsum[tid];
  else       *tp += tsum[tid];
}

// ---------------- agg[b][d] = (sum partial0 + sum tpart)/1024 ----------------
__global__ __launch_bounds__(512)
void agg_final(const float* __restrict__ partial0, const float* __restrict__ tpart,
               float* __restrict__ agg) {
  const int b = blockIdx.x, d = threadIdx.x;
  float s = 0.f;
  for (int c = 0; c < 128; ++c) s += partial0[((size_t)c * 16 + b) * 512 + d];
  for (int k = 0; k < 128; ++k) {     // wid = l*32 + b*2 + half
    int wid = (k >> 1) * 32 + b * 2 + (k & 1);
    s += tpart[(size_t)wid * 512 + d];
  }
  agg[b * 512 + d] = s * (1.0f / 1024.0f);
}

// ---------------- final MLP ---------------------------------------------------
__global__ __launch_bounds__(256)
void mlp1(const float* __restrict__ agg, const float* __restrict__ W1t,
          const float* __restrict__ b1, float* __restrict__ hdn) {
  const int lane = threadIdx.x & 63;
  const int o = blockIdx.x * 4 + (threadIdx.x >> 6);
  const int b = lane & 15, q = lane >> 4;
  const float4* wp = (const float4*)(W1t + (size_t)o * 512 + q * 128);
  const float4* ap = (const float4*)(agg + b * 512 + q * 128);
  float acc = 0.f;
#pragma unroll
  for (int i = 0; i < 32; ++i) {
    float4 w = wp[i], a = ap[i];
    acc += w.x * a.x + w.y * a.y + w.z * a.z + w.w * a.w;
  }
  acc += __shfl_xor(acc, 16);
  acc += __shfl_xor(acc, 32);
  if (lane < 16) hdn[b * 1024 + o] = fmaxf(acc + b1[o], 0.f);
}

__global__ __launch_bounds__(256)
void mlp2(const float* __restrict__ hdn, const float* __restrict__ W2t,
          const float* __restrict__ b2, float* __restrict__ out) {
  const int lane = threadIdx.x & 63;
  const int o = blockIdx.x * 4 + (threadIdx.x >> 6);
  const int b = lane & 15, q = lane >> 4;
  const float4* wp = (const float4*)(W2t + (size_t)o * 1024 + q * 256);
  const float4* hp = (const float4*)(hdn + b * 1024 + q * 256);
  float acc = 0.f;
#pragma unroll
  for (int i = 0; i < 64; ++i) {
    float4 w = wp[i], h = hp[i];
    acc += w.x * h.x + w.y * h.y + w.z * h.z + w.w * h.w;
  }
  acc += __shfl_xor(acc, 16);
  acc += __shfl_xor(acc, 32);
  if (lane < 16) out[b * 512 + o] = acc + b2[o];
}

// ---------------- launch -----------------------------------------------------
extern "C" void kernel_launch(void* const* d_in, const int* in_sizes, int n_in,
                              void* d_out, int out_size, void* d_ws, size_t ws_size,
                              hipStream_t stream) {
  const float* what   = (const float*)d_in[0];
  const float* action = (const float*)d_in[1];
  const float* result = (const float*)d_in[2];
  const float* Wq = (const float*)d_in[3];
  const float* bq = (const float*)d_in[4];
  const float* Wk = (const float*)d_in[5];
  const float* bk = (const float*)d_in[6];
  const float* Wv = (const float*)d_in[7];
  const float* bv = (const float*)d_in[8];
  const float* Whop = (const float*)d_in[9];
  const float* bhop = (const float*)d_in[10];
  const float* W1 = (const float*)d_in[11];
  const float* b1 = (const float*)d_in[12];
  const float* W2 = (const float*)d_in[13];
  const float* b2 = (const float*)d_in[14];
  float* out = (float*)d_out;

  char* ws = (char*)d_ws;
  bf16*  xb     = (bf16*)(ws + 0);               // 16,777,216 B
  bf16*  QKW    = (bf16*)(ws + 16777216);        // 50,331,648 B (ld=1536)
  // WhopTb/Wvb alias QKW region: consumed by gemm_plain before hop 0 writes QKW
  bf16*  WhopTb = (bf16*)(ws + 16777216);        //  1,572,864 B (alias)
  bf16*  Wvb    = (bf16*)(ws + 18350080);        //    524,288 B (alias)
  bf16*  WtQK   = (bf16*)(ws + 67108864);        //  1,048,576 B
  bf16*  WvwT   = (bf16*)(ws + 68157440);        //  1,572,864 B (3 hops)
  float* bcat   = (float*)(ws + 69730304);       //      4,096 B
  float* bvw    = (float*)(ws + 69734400);       //      6,144 B
  float* W1t    = (float*)(ws + 69740544);       //  2,097,152 B
  float* W2t    = (float*)(ws + 71837696);       //  2,097,152 B
  float* part0  = (float*)(ws + 73934848);       //  4,194,304 B (128*16*512 f32)
  float* tpart  = (float*)(ws + 78129152);       //  4,194,304 B (2048*512 f32)
  float* agg    = (float*)(ws + 82323456);       //     32,768 B
  float* hdn    = (float*)(ws + 82356224);       //     65,536 B

  prep_weights<<<10244, 256, 0, stream>>>(Wq, Wk, bq, bk, Wv, Whop, W1, W2,
                                          WtQK, bcat, WhopTb, Wvb, W1t, W2t);
  bvw_kernel<<<384, 256, 0, stream>>>(bv, Whop, bvw);
  gemm_plain<<<dim3(12, 4), 256, 0, stream>>>(WhopTb, Wvb, WvwT);
  nodes_kernel<<<dim3(128, 16), 128, 0, stream>>>((const float4*)what, (const float4*)action,
                                                  (const float4*)result, (bf16x4*)xb,
                                                  (float4*)part0);
  for (int h = 0; h < 3; ++h) {
    gemm_qkw<<<dim3(128, 12), 256, 0, stream>>>(xb, WtQK, WvwT + h * 262144,
                                                bcat, bvw + h * 512, QKW);
    attn_mix<<<2048, 512, 0, stream>>>(QKW, xb, bhop + h * 512, tpart, h == 0 ? 1 : 0);
  }
  agg_final<<<16, 512, 0, stream>>>(part0, tpart, agg);
  mlp1<<<256, 256, 0, stream>>>(agg, W1t, b1, hdn);
  mlp2<<<128, 256, 0, stream>>>(hdn, W2t, b2, out);
}

// Round 6
// 303.882 us; speedup vs baseline: 1.3410x; 1.3410x over previous
//
#include <hip/hip_runtime.h>
#include <stdint.h>

// DreamGraphReasoner on MI355X (gfx950)
// Residual stream kept bf16-only (xb). Exact f32 mean maintained separately:
// mean(x3) = mean(x0) + sum_h mean(t_h), with partial sums fused into
// nodes_kernel (x0) and attn_mix (t_h, per-wave LDS slices, NO atomics).
// Sparse attention: node n=(g,l) attends to {(g',l): g'!=g} U {(g,l+1) if l<63}
// Fusion: attended@Whop = attn@(V@Whop)  =>  QKV GEMM emits Q|K|VW_h directly.

typedef __bf16 bf16;
typedef __bf16 bf16x8 __attribute__((ext_vector_type(8)));
typedef __bf16 bf16x4 __attribute__((ext_vector_type(4)));
typedef float  f32x4  __attribute__((ext_vector_type(4)));

__device__ __forceinline__ void gload_lds16(const void* g, void* l) {
  __builtin_amdgcn_global_load_lds(
      (__attribute__((address_space(1))) void*)(size_t)(g),
      (__attribute__((address_space(3))) void*)(l), 16, 0, 0);
}

// ---------------- weight prep (coalesced reads; scattered writes L2-combine) --
__global__ void prep_weights(const float* __restrict__ Wq, const float* __restrict__ Wk,
                             const float* __restrict__ bq, const float* __restrict__ bk,
                             const float* __restrict__ Wv, const float* __restrict__ Whop,
                             const float* __restrict__ W1, const float* __restrict__ W2,
                             bf16* __restrict__ WtQK, float* __restrict__ bcat,
                             bf16* __restrict__ WhopTb, bf16* __restrict__ Wvb,
                             float* __restrict__ W1t, float* __restrict__ W2t) {
  int t = blockIdx.x * 256 + threadIdx.x;
  if (t < 524288) {                        // WtQK[sel*512+c][k] = W[k][c]
    int sel = t >> 18, k = (t >> 9) & 511, c = t & 511;
    const float* W = sel ? Wk : Wq;
    WtQK[(size_t)(sel * 512 + c) * 512 + k] = (bf16)W[k * 512 + c];
  } else if (t < 1048576) {                // W1t[o][d] = W1[d][o]
    int u = t - 524288;
    int d = u >> 10, o = u & 1023;
    W1t[(size_t)o * 512 + d] = W1[d * 1024 + o];
  } else if (t < 1572864) {                // W2t[o][d] = W2[d][o]
    int u = t - 1048576;
    int d = u >> 9, o = u & 511;
    W2t[(size_t)o * 1024 + d] = W2[d * 512 + o];
  } else if (t < 1573888) {
    int u = t - 1572864;
    bcat[u] = (u < 512) ? bq[u] : bk[u - 512];
  } else if (t < 2360320) {                // WhopTb[h*512+c][d] = Whop[h][d][c]
    int u = t - 1573888;
    int h = u >> 18, rem = u & 262143;
    int d = rem >> 9, c = rem & 511;
    WhopTb[(size_t)h * 262144 + (size_t)c * 512 + d] = (bf16)Whop[h * 262144 + d * 512 + c];
  } else if (t < 2622464) {                // Wvb = bf16(Wv)
    int u = t - 2360320;
    Wvb[u] = (bf16)Wv[u];
  }
}

// ---------------- bvw[h][c] = sum_d bv[d] * Whop[h][d][c]  (wave per output) --
__global__ __launch_bounds__(256)
void bvw_kernel(const float* __restrict__ bv, const float* __restrict__ Whop,
                float* __restrict__ bvw) {
  int w = blockIdx.x * 4 + (threadIdx.x >> 6);  // 0..1535
  int lane = threadIdx.x & 63;
  int h = w >> 9, c = w & 511;
  int d0 = lane * 8;
  const float* wh = Whop + h * 262144 + c;
  float p = 0.f;
#pragma unroll
  for (int i = 0; i < 8; ++i) p += bv[d0 + i] * wh[(d0 + i) * 512];
#pragma unroll
  for (int off = 32; off; off >>= 1) p += __shfl_xor(p, off);
  if (lane == 0) bvw[w] = p;
}

// ---------------- node embeddings + fused x0 mean partials -------------------
__global__ __launch_bounds__(128)
void nodes_kernel(const float4* __restrict__ w, const float4* __restrict__ a,
                  const float4* __restrict__ r, bf16x4* __restrict__ xb,
                  float4* __restrict__ partial0) {
  const int c = blockIdx.x;   // 0..127
  const int b = blockIdx.y;   // 0..15
  const int dq = threadIdx.x; // 0..127 (d = dq*4)
  float4 s = (float4){0.f, 0.f, 0.f, 0.f};
#pragma unroll 2
  for (int n = c * 8; n < c * 8 + 8; ++n) {
    size_t idx = ((size_t)(n * 16 + b)) * 128 + dq;   // float4 index
    float4 vw = w[idx], va = a[idx], vr = r[idx];
    float4 v;
    v.x = (vw.x + va.x + vr.x) * (1.f / 3.f);
    v.y = (vw.y + va.y + vr.y) * (1.f / 3.f);
    v.z = (vw.z + va.z + vr.z) * (1.f / 3.f);
    v.w = (vw.w + va.w + vr.w) * (1.f / 3.f);
    bf16x4 bv4;
    bv4[0] = (bf16)v.x; bv4[1] = (bf16)v.y; bv4[2] = (bf16)v.z; bv4[3] = (bf16)v.w;
    xb[idx] = bv4;
    s.x += v.x; s.y += v.y; s.z += v.z; s.w += v.w;
  }
  partial0[((size_t)c * 16 + b) * 128 + dq] = s;
}

// ---------------- plain bf16 MFMA GEMM: out(1536x512) = A @ Bt^T -------------
__global__ __launch_bounds__(256)
void gemm_plain(const bf16* __restrict__ A, const bf16* __restrict__ Bt,
                bf16* __restrict__ out) {
  constexpr int BK = 32;
  __shared__ __align__(16) bf16 As[128 * BK];
  __shared__ __align__(16) bf16 Bs[128 * BK];
  const int tid = threadIdx.x;
  const int wave = tid >> 6, lane = tid & 63;
  const int wr = wave >> 1, wc = wave & 1;
  const int m0 = blockIdx.x * 128;
  const int n0 = blockIdx.y * 128;
  const int srow = lane >> 2;
  const int skg = ((lane & 3) ^ ((lane >> 3) & 3)) * 8;
  const int fr = lane & 15;
  const int kq = (((lane >> 4) ^ ((lane >> 1) & 3)) & 3) * 8;

  f32x4 acc[4][4];
#pragma unroll
  for (int i = 0; i < 4; ++i)
#pragma unroll
    for (int j = 0; j < 4; ++j) acc[i][j] = (f32x4){0.f, 0.f, 0.f, 0.f};

  for (int kt = 0; kt < 512; kt += BK) {
    __syncthreads();
#pragma unroll
    for (int i = 0; i < 2; ++i) {
      int ch = wave * 2 + i;
      int row = ch * 16 + srow;
      gload_lds16(A + (size_t)(m0 + row) * 512 + kt + skg, &As[ch * 16 * BK]);
      gload_lds16(Bt + (size_t)(n0 + row) * 512 + kt + skg, &Bs[ch * 16 * BK]);
    }
    __syncthreads();

    bf16x8 af[4], bg[4];
#pragma unroll
    for (int i = 0; i < 4; ++i)
      af[i] = *(const bf16x8*)&As[(wr * 64 + i * 16 + fr) * BK + kq];
#pragma unroll
    for (int j = 0; j < 4; ++j)
      bg[j] = *(const bf16x8*)&Bs[(wc * 64 + j * 16 + fr) * BK + kq];
#pragma unroll
    for (int i = 0; i < 4; ++i)
#pragma unroll
      for (int j = 0; j < 4; ++j)
        acc[i][j] = __builtin_amdgcn_mfma_f32_16x16x32_bf16(af[i], bg[j], acc[i][j], 0, 0, 0);
  }

#pragma unroll
  for (int i = 0; i < 4; ++i) {
    int grow0 = m0 + wr * 64 + i * 16 + (lane >> 4) * 4;
#pragma unroll
    for (int j = 0; j < 4; ++j) {
      int gcol = n0 + wc * 64 + j * 16 + fr;
#pragma unroll
      for (int q = 0; q < 4; ++q)
        out[(size_t)(grow0 + q) * 512 + gcol] = (bf16)acc[i][j][q];
    }
  }
}

// ---------------- bf16 MFMA GEMM: QKW = A(16384x512) @ [WqT|WkT|WvwT]^T + bias
__global__ __launch_bounds__(256)
void gemm_qkw(const bf16* __restrict__ A, const bf16* __restrict__ BtQK,
              const bf16* __restrict__ BtVW, const float* __restrict__ biasQK,
              const float* __restrict__ biasVW, bf16* __restrict__ out) {
  constexpr int BK = 32;
  __shared__ __align__(16) bf16 As[128 * BK];
  __shared__ __align__(16) bf16 Bs[128 * BK];
  const int tid = threadIdx.x;
  const int wave = tid >> 6, lane = tid & 63;
  const int wr = wave >> 1, wc = wave & 1;
  const int m0 = blockIdx.x * 128;
  const int n0 = blockIdx.y * 128;
  const bf16* Bt = (n0 < 1024) ? BtQK : (BtVW - (size_t)1024 * 512);
  const float* bias = (n0 < 1024) ? biasQK : (biasVW - 1024);

  const int srow = lane >> 2;
  const int skg = ((lane & 3) ^ ((lane >> 3) & 3)) * 8;
  const int fr = lane & 15;
  const int kq = (((lane >> 4) ^ ((lane >> 1) & 3)) & 3) * 8;

  f32x4 acc[4][4];
#pragma unroll
  for (int i = 0; i < 4; ++i)
#pragma unroll
    for (int j = 0; j < 4; ++j) acc[i][j] = (f32x4){0.f, 0.f, 0.f, 0.f};

  for (int kt = 0; kt < 512; kt += BK) {
    __syncthreads();
#pragma unroll
    for (int i = 0; i < 2; ++i) {
      int ch = wave * 2 + i;
      int row = ch * 16 + srow;
      gload_lds16(A + (size_t)(m0 + row) * 512 + kt + skg, &As[ch * 16 * BK]);
      gload_lds16(Bt + (size_t)(n0 + row) * 512 + kt + skg, &Bs[ch * 16 * BK]);
    }
    __syncthreads();

    bf16x8 af[4], bg[4];
#pragma unroll
    for (int i = 0; i < 4; ++i)
      af[i] = *(const bf16x8*)&As[(wr * 64 + i * 16 + fr) * BK + kq];
#pragma unroll
    for (int j = 0; j < 4; ++j)
      bg[j] = *(const bf16x8*)&Bs[(wc * 64 + j * 16 + fr) * BK + kq];
#pragma unroll
    for (int i = 0; i < 4; ++i)
#pragma unroll
      for (int j = 0; j < 4; ++j)
        acc[i][j] = __builtin_amdgcn_mfma_f32_16x16x32_bf16(af[i], bg[j], acc[i][j], 0, 0, 0);
  }

#pragma unroll
  for (int i = 0; i < 4; ++i) {
    int grow0 = m0 + wr * 64 + i * 16 + (lane >> 4) * 4;
#pragma unroll
    for (int j = 0; j < 4; ++j) {
      int gcol = n0 + wc * 64 + j * 16 + fr;
      float bvv = bias[gcol];
#pragma unroll
      for (int q = 0; q < 4; ++q)
        out[(size_t)(grow0 + q) * 1536 + gcol] = (bf16)(acc[i][j][q] + bvv);
    }
  }
}

// ---------------- sparse masked attention + hop epilogue + t-mean partials ---
// 512-thread blocks: 8 waves = 8 dreams per (l,b). XCD-chunked block swizzle.
// t-mean partials via disjoint per-wave LDS slices (no atomics, 1 barrier).
// Slice layout permutation: wave w, lane l, elem i (d = 8l+i) stored at
// p = (i<4 ? 4l+i : 256+4l+(i-4)) so stores hit banks 0..31 across lanes and
// the cross-wave read (p(tid)) is 2-way max.
__global__ __launch_bounds__(512)
void attn_mix(const bf16* __restrict__ QKW, bf16* __restrict__ xb,
              const float* __restrict__ bhop, float* __restrict__ tpart,
              int first) {
  __shared__ float slice[8 * 512];
  const int tid = threadIdx.x;
  const int bid = blockIdx.x;
  const int wid = ((bid & 7) << 8) | (bid >> 3);   // 256 blocks per XCD chunk
  const int lane = tid & 63;
  const int wv = tid >> 6;
  const int l = wid >> 5;
  const int b = (wid >> 1) & 15;
  const int g = ((wid & 1) << 3) | wv;
  const int r = (((g << 6) | l) << 4) | b;

  bf16x8 qv = *(const bf16x8*)(QKW + (size_t)r * 1536 + lane * 8);
  float qf[8];
#pragma unroll
  for (int i = 0; i < 8; ++i) qf[i] = (float)qv[i];

  int rows[17];
#pragma unroll
  for (int j = 0; j < 16; ++j) rows[j] = (((j << 6) | l) << 4) | b;
  rows[16] = (l < 63) ? (r + 16) : r;

  float s[17];
#pragma unroll
  for (int j = 0; j < 17; ++j) {
    const bf16* Krow = QKW + (size_t)rows[j] * 1536 + 512;
    bf16x8 kv = *(const bf16x8*)(Krow + lane * 8);
    float p = 0.f;
#pragma unroll
    for (int i = 0; i < 8; ++i) p += qf[i] * (float)kv[i];
#pragma unroll
    for (int off = 32; off; off >>= 1) p += __shfl_xor(p, off);
    p *= 0.044194173824159216f;  // 1/sqrt(512)
    bool valid = (j < 16) ? (j != g) : (l < 63);
    s[j] = valid ? p : -1e30f;
  }

  float mx = -1e30f;
#pragma unroll
  for (int j = 0; j < 17; ++j) mx = fmaxf(mx, s[j]);
  float pr[17], sum = 0.f;
#pragma unroll
  for (int j = 0; j < 17; ++j) { pr[j] = __expf(s[j] - mx); sum += pr[j]; }
  float inv = 1.f / sum;

  float acc[8] = {0, 0, 0, 0, 0, 0, 0, 0};
#pragma unroll
  for (int j = 0; j < 17; ++j) {
    const bf16* Vrow = QKW + (size_t)rows[j] * 1536 + 1024;
    bf16x8 vv = *(const bf16x8*)(Vrow + lane * 8);
    float w = pr[j] * inv;
#pragma unroll
    for (int i = 0; i < 8; ++i) acc[i] += w * (float)vv[i];
  }

  // epilogue: t = relu(mix+bh); xb += t (bf16 RMW, row owned by this wave)
  const int d0 = lane * 8;
  size_t idx = (size_t)r * 512 + d0;
  bf16x8 xo = *(const bf16x8*)(xb + idx);
  float4 bh0 = *(const float4*)(bhop + d0);
  float4 bh1 = *(const float4*)(bhop + d0 + 4);
  float bh[8] = {bh0.x, bh0.y, bh0.z, bh0.w, bh1.x, bh1.y, bh1.z, bh1.w};
  bf16x8 ov;
  float t[8];
#pragma unroll
  for (int i = 0; i < 8; ++i) {
    t[i] = fmaxf(acc[i] + bh[i], 0.f);
    ov[i] = (bf16)((float)xo[i] + t[i]);
  }
  *(bf16x8*)(xb + idx) = ov;

  // per-wave slice stores (disjoint, conflict-free), then cross-wave sum
  *(float4*)&slice[wv * 512 + lane * 4]       = (float4){t[0], t[1], t[2], t[3]};
  *(float4*)&slice[wv * 512 + 256 + lane * 4] = (float4){t[4], t[5], t[6], t[7]};
  __syncthreads();
  const int ll = tid >> 3, ii = tid & 7;
  const int p = (ii < 4) ? (ll * 4 + ii) : (256 + ll * 4 + (ii - 4));
  float s2 = 0.f;
#pragma unroll
  for (int w2 = 0; w2 < 8; ++w2) s2 += slice[w2 * 512 + p];
  float* tp = tpart + (size_t)wid * 512 + tid;
  if (first) *tp = s2;
  else       *tp += s2;
}

// ---------------- agg[b][d] = (sum partial0 + sum tpart)/1024 ----------------
__global__ __launch_bounds__(128)
void agg_final(const float* __restrict__ partial0, const float* __restrict__ tpart,
               float* __restrict__ agg) {
  const int b = blockIdx.x, dc = blockIdx.y;
  const int d = dc * 128 + threadIdx.x;
  float s = 0.f;
  for (int c = 0; c < 128; ++c) s += partial0[((size_t)c * 16 + b) * 512 + d];
  for (int k = 0; k < 128; ++k) {     // wid = l*32 + b*2 + half
    int wid = (k >> 1) * 32 + b * 2 + (k & 1);
    s += tpart[(size_t)wid * 512 + d];
  }
  agg[b * 512 + d] = s * (1.0f / 1024.0f);
}

// ---------------- final MLP ---------------------------------------------------
__global__ __launch_bounds__(256)
void mlp1(const float* __restrict__ agg, const float* __restrict__ W1t,
          const float* __restrict__ b1, float* __restrict__ hdn) {
  const int lane = threadIdx.x & 63;
  const int o = blockIdx.x * 4 + (threadIdx.x >> 6);
  const int b = lane & 15, q = lane >> 4;
  const float4* wp = (const float4*)(W1t + (size_t)o * 512 + q * 128);
  const float4* ap = (const float4*)(agg + b * 512 + q * 128);
  float acc = 0.f;
#pragma unroll
  for (int i = 0; i < 32; ++i) {
    float4 w = wp[i], a = ap[i];
    acc += w.x * a.x + w.y * a.y + w.z * a.z + w.w * a.w;
  }
  acc += __shfl_xor(acc, 16);
  acc += __shfl_xor(acc, 32);
  if (lane < 16) hdn[b * 1024 + o] = fmaxf(acc + b1[o], 0.f);
}

__global__ __launch_bounds__(256)
void mlp2(const float* __restrict__ hdn, const float* __restrict__ W2t,
          const float* __restrict__ b2, float* __restrict__ out) {
  const int lane = threadIdx.x & 63;
  const int o = blockIdx.x * 4 + (threadIdx.x >> 6);
  const int b = lane & 15, q = lane >> 4;
  const float4* wp = (const float4*)(W2t + (size_t)o * 1024 + q * 256);
  const float4* hp = (const float4*)(hdn + b * 1024 + q * 256);
  float acc = 0.f;
#pragma unroll
  for (int i = 0; i < 64; ++i) {
    float4 w = wp[i], h = hp[i];
    acc += w.x * h.x + w.y * h.y + w.z * h.z + w.w * h.w;
  }
  acc += __shfl_xor(acc, 16);
  acc += __shfl_xor(acc, 32);
  if (lane < 16) out[b * 512 + o] = acc + b2[o];
}

// ---------------- launch -----------------------------------------------------
extern "C" void kernel_launch(void* const* d_in, const int* in_sizes, int n_in,
                              void* d_out, int out_size, void* d_ws, size_t ws_size,
                              hipStream_t stream) {
  const float* what   = (const float*)d_in[0];
  const float* action = (const float*)d_in[1];
  const float* result = (const float*)d_in[2];
  const float* Wq = (const float*)d_in[3];
  const float* bq = (const float*)d_in[4];
  const float* Wk = (const float*)d_in[5];
  const float* bk = (const float*)d_in[6];
  const float* Wv = (const float*)d_in[7];
  const float* bv = (const float*)d_in[8];
  const float* Whop = (const float*)d_in[9];
  const float* bhop = (const float*)d_in[10];
  const float* W1 = (const float*)d_in[11];
  const float* b1 = (const float*)d_in[12];
  const float* W2 = (const float*)d_in[13];
  const float* b2 = (const float*)d_in[14];
  float* out = (float*)d_out;

  char* ws = (char*)d_ws;
  bf16*  xb     = (bf16*)(ws + 0);               // 16,777,216 B
  bf16*  QKW    = (bf16*)(ws + 16777216);        // 50,331,648 B (ld=1536)
  // WhopTb/Wvb alias QKW region: consumed by gemm_plain before hop 0 writes QKW
  bf16*  WhopTb = (bf16*)(ws + 16777216);        //  1,572,864 B (alias)
  bf16*  Wvb    = (bf16*)(ws + 18350080);        //    524,288 B (alias)
  bf16*  WtQK   = (bf16*)(ws + 67108864);        //  1,048,576 B
  bf16*  WvwT   = (bf16*)(ws + 68157440);        //  1,572,864 B (3 hops)
  float* bcat   = (float*)(ws + 69730304);       //      4,096 B
  float* bvw    = (float*)(ws + 69734400);       //      6,144 B
  float* W1t    = (float*)(ws + 69740544);       //  2,097,152 B
  float* W2t    = (float*)(ws + 71837696);       //  2,097,152 B
  float* part0  = (float*)(ws + 73934848);       //  4,194,304 B (128*16*512 f32)
  float* tpart  = (float*)(ws + 78129152);       //  4,194,304 B (2048*512 f32)
  float* agg    = (float*)(ws + 82323456);       //     32,768 B
  float* hdn    = (float*)(ws + 82356224);       //     65,536 B

  prep_weights<<<10244, 256, 0, stream>>>(Wq, Wk, bq, bk, Wv, Whop, W1, W2,
                                          WtQK, bcat, WhopTb, Wvb, W1t, W2t);
  bvw_kernel<<<384, 256, 0, stream>>>(bv, Whop, bvw);
  gemm_plain<<<dim3(12, 4), 256, 0, stream>>>(WhopTb, Wvb, WvwT);
  nodes_kernel<<<dim3(128, 16), 128, 0, stream>>>((const float4*)what, (const float4*)action,
                                                  (const float4*)result, (bf16x4*)xb,
                                                  (float4*)part0);
  for (int h = 0; h < 3; ++h) {
    gemm_qkw<<<dim3(128, 12), 256, 0, stream>>>(xb, WtQK, WvwT + h * 262144,
                                                bcat, bvw + h * 512, QKW);
    attn_mix<<<2048, 512, 0, stream>>>(QKW, xb, bhop + h * 512, tpart, h == 0 ? 1 : 0);
  }
  agg_final<<<dim3(16, 4), 128, 0, stream>>>(part0, tpart, agg);
  mlp1<<<256, 256, 0, stream>>>(agg, W1t, b1, hdn);
  mlp2<<<128, 256, 0, stream>>>(hdn, W2t, b2, out);
}